// Round 1
// baseline (103.414 us; speedup 1.0000x reference)
//
#include <hip/hip_runtime.h>

// B=16384 rows, D=4096 fp32 features. One wave (64 lanes) per row.
// Block = 256 threads = 4 waves = 4 rows. Grid = B/4 = 4096 blocks.
// Memory-bound: 512 MB read -> ~81 us at 6.3 TB/s achievable.

__global__ __launch_bounds__(256) void loss_synonymy_kernel(
    const float* __restrict__ S1,
    const float* __restrict__ S2,
    const int*   __restrict__ labels,
    float* __restrict__ out,
    int B, int D)
{
    const int wave = threadIdx.x >> 6;   // 0..3
    const int lane = threadIdx.x & 63;
    const long long row = (long long)blockIdx.x * 4 + wave;

    __shared__ float part[4];

    float acc = 0.0f;
    if (row < B) {
        const float4* __restrict__ p1 = (const float4*)(S1 + row * (long long)D);
        const float4* __restrict__ p2 = (const float4*)(S2 + row * (long long)D);
        const int nvec = D >> 2;  // 1024 float4 per row
        #pragma unroll 4
        for (int i = lane; i < nvec; i += 64) {
            float4 a = p1[i];
            float4 b = p2[i];
            float dx = a.x - b.x;
            float dy = a.y - b.y;
            float dz = a.z - b.z;
            float dw = a.w - b.w;
            acc = fmaf(dx, dx, acc);
            acc = fmaf(dy, dy, acc);
            acc = fmaf(dz, dz, acc);
            acc = fmaf(dw, dw, acc);
        }
        // 64-lane wave reduction
        #pragma unroll
        for (int off = 32; off > 0; off >>= 1)
            acc += __shfl_down(acc, off, 64);

        if (lane == 0) {
            float dist = sqrtf(acc);
            float t = tanhf(dist);
            float s = (labels[row] == 1) ? -t : t;
            part[wave] = fmaxf(0.0f, 1.0f + s);
        }
    } else {
        if (lane == 0) part[wave] = 0.0f;
    }
    __syncthreads();
    if (threadIdx.x == 0) {
        atomicAdd(out, part[0] + part[1] + part[2] + part[3]);
    }
}

extern "C" void kernel_launch(void* const* d_in, const int* in_sizes, int n_in,
                              void* d_out, int out_size, void* d_ws, size_t ws_size,
                              hipStream_t stream) {
    const float* S1     = (const float*)d_in[0];
    const float* S2     = (const float*)d_in[1];
    const int*   labels = (const int*)d_in[2];
    float* out = (float*)d_out;

    const int B = in_sizes[2];            // 16384 labels
    const int D = in_sizes[0] / B;        // 4096

    // d_out is poisoned once and never re-poisoned between timed replays;
    // we accumulate with atomics, so zero it ourselves every call.
    hipMemsetAsync(out, 0, sizeof(float), stream);

    const int rows_per_block = 4;
    const int grid = (B + rows_per_block - 1) / rows_per_block;
    loss_synonymy_kernel<<<grid, 256, 0, stream>>>(S1, S2, labels, out, B, D);
}

// Round 3
// 98.654 us; speedup vs baseline: 1.0482x; 1.0482x over previous
//
#include <hip/hip_runtime.h>

// B=16384 rows, D=4096 fp32 features. One wave (64 lanes) per row.
// Block = 256 threads = 4 waves = 4 rows. Grid = B/4 = 4096 blocks.
// Memory-bound: 512 MB read -> ~81 us at 6.3 TB/s achievable.
// R1: nontemporal loads (streaming, 512MB > 256MB L3), 4 accumulators,
//     deeper unroll for more loads in flight.
// R2: __builtin_nontemporal_load needs a native vector type, not
//     HIP_vector_type<float,4> — use ext_vector_type(4).

typedef float f32x4 __attribute__((ext_vector_type(4)));

__global__ __launch_bounds__(256) void loss_synonymy_kernel(
    const float* __restrict__ S1,
    const float* __restrict__ S2,
    const int*   __restrict__ labels,
    float* __restrict__ out,
    int B, int D)
{
    const int wave = threadIdx.x >> 6;   // 0..3
    const int lane = threadIdx.x & 63;
    const long long row = (long long)blockIdx.x * 4 + wave;

    __shared__ float part[4];

    float ax = 0.0f, ay = 0.0f, az = 0.0f, aw = 0.0f;
    if (row < B) {
        const f32x4* __restrict__ p1 = (const f32x4*)(S1 + row * (long long)D);
        const f32x4* __restrict__ p2 = (const f32x4*)(S2 + row * (long long)D);
        const int nvec = D >> 2;  // 1024 float4 per row
        #pragma unroll 8
        for (int i = lane; i < nvec; i += 64) {
            f32x4 a = __builtin_nontemporal_load(&p1[i]);
            f32x4 b = __builtin_nontemporal_load(&p2[i]);
            float dx = a.x - b.x;
            float dy = a.y - b.y;
            float dz = a.z - b.z;
            float dw = a.w - b.w;
            ax = fmaf(dx, dx, ax);
            ay = fmaf(dy, dy, ay);
            az = fmaf(dz, dz, az);
            aw = fmaf(dw, dw, aw);
        }
        float acc = (ax + ay) + (az + aw);
        // 64-lane wave reduction
        #pragma unroll
        for (int off = 32; off > 0; off >>= 1)
            acc += __shfl_down(acc, off, 64);

        if (lane == 0) {
            float dist = sqrtf(acc);
            float t = tanhf(dist);
            float s = (labels[row] == 1) ? -t : t;
            part[wave] = fmaxf(0.0f, 1.0f + s);
        }
    } else {
        if (lane == 0) part[wave] = 0.0f;
    }
    __syncthreads();
    if (threadIdx.x == 0) {
        atomicAdd(out, part[0] + part[1] + part[2] + part[3]);
    }
}

extern "C" void kernel_launch(void* const* d_in, const int* in_sizes, int n_in,
                              void* d_out, int out_size, void* d_ws, size_t ws_size,
                              hipStream_t stream) {
    const float* S1     = (const float*)d_in[0];
    const float* S2     = (const float*)d_in[1];
    const int*   labels = (const int*)d_in[2];
    float* out = (float*)d_out;

    const int B = in_sizes[2];            // 16384 labels
    const int D = in_sizes[0] / B;        // 4096

    // d_out is poisoned once and never re-poisoned between timed replays;
    // we accumulate with atomics, so zero it ourselves every call.
    (void)hipMemsetAsync(out, 0, sizeof(float), stream);

    const int rows_per_block = 4;
    const int grid = (B + rows_per_block - 1) / rows_per_block;
    loss_synonymy_kernel<<<grid, 256, 0, stream>>>(S1, S2, labels, out, B, D);
}

// Round 4
// 87.368 us; speedup vs baseline: 1.1837x; 1.1292x over previous
//
#include <hip/hip_runtime.h>

// B=16384 rows, D=4096 fp32 features. One wave (64 lanes) per row.
// Block = 256 threads = 4 waves = 4 rows. Grid = B/4 = 4096 blocks.
// Memory-bound: 537 MB read -> ~85 us at 6.3 TB/s achievable.
// R1/R2: nontemporal loads (streaming, 512MB > 256MB L3), 4 accumulators,
//        unroll 8 for MLP. 98.6 us = 5.44 TB/s.
// R3: kill the memset dispatch + same-address atomic hotspot:
//     kernel1 plain-stores one partial per block into d_ws (all slots
//     written every call -> no init needed), kernel2 (1 block) reduces.

typedef float f32x4 __attribute__((ext_vector_type(4)));

__global__ __launch_bounds__(256) void loss_synonymy_partial(
    const float* __restrict__ S1,
    const float* __restrict__ S2,
    const int*   __restrict__ labels,
    float* __restrict__ partials,
    int B, int D)
{
    const int wave = threadIdx.x >> 6;   // 0..3
    const int lane = threadIdx.x & 63;
    const long long row = (long long)blockIdx.x * 4 + wave;

    __shared__ float part[4];

    float ax = 0.0f, ay = 0.0f, az = 0.0f, aw = 0.0f;
    if (row < B) {
        const f32x4* __restrict__ p1 = (const f32x4*)(S1 + row * (long long)D);
        const f32x4* __restrict__ p2 = (const f32x4*)(S2 + row * (long long)D);
        const int nvec = D >> 2;  // 1024 float4 per row
        #pragma unroll 8
        for (int i = lane; i < nvec; i += 64) {
            f32x4 a = __builtin_nontemporal_load(&p1[i]);
            f32x4 b = __builtin_nontemporal_load(&p2[i]);
            float dx = a.x - b.x;
            float dy = a.y - b.y;
            float dz = a.z - b.z;
            float dw = a.w - b.w;
            ax = fmaf(dx, dx, ax);
            ay = fmaf(dy, dy, ay);
            az = fmaf(dz, dz, az);
            aw = fmaf(dw, dw, aw);
        }
        float acc = (ax + ay) + (az + aw);
        // 64-lane wave reduction
        #pragma unroll
        for (int off = 32; off > 0; off >>= 1)
            acc += __shfl_down(acc, off, 64);

        if (lane == 0) {
            float dist = sqrtf(acc);
            float t = tanhf(dist);
            float s = (labels[row] == 1) ? -t : t;
            part[wave] = fmaxf(0.0f, 1.0f + s);
        }
    } else {
        if (lane == 0) part[wave] = 0.0f;
    }
    __syncthreads();
    if (threadIdx.x == 0) {
        partials[blockIdx.x] = part[0] + part[1] + part[2] + part[3];
    }
}

__global__ __launch_bounds__(256) void loss_synonymy_reduce(
    const float* __restrict__ partials,
    float* __restrict__ out,
    int n)
{
    const int lane = threadIdx.x & 63;
    const int wave = threadIdx.x >> 6;

    float acc = 0.0f;
    for (int i = threadIdx.x; i < n; i += 256)
        acc += partials[i];

    #pragma unroll
    for (int off = 32; off > 0; off >>= 1)
        acc += __shfl_down(acc, off, 64);

    __shared__ float part[4];
    if (lane == 0) part[wave] = acc;
    __syncthreads();
    if (threadIdx.x == 0)
        out[0] = (part[0] + part[1]) + (part[2] + part[3]);
}

extern "C" void kernel_launch(void* const* d_in, const int* in_sizes, int n_in,
                              void* d_out, int out_size, void* d_ws, size_t ws_size,
                              hipStream_t stream) {
    const float* S1     = (const float*)d_in[0];
    const float* S2     = (const float*)d_in[1];
    const int*   labels = (const int*)d_in[2];
    float* out      = (float*)d_out;
    float* partials = (float*)d_ws;

    const int B = in_sizes[2];            // 16384 labels
    const int D = in_sizes[0] / B;        // 4096

    const int rows_per_block = 4;
    const int grid = (B + rows_per_block - 1) / rows_per_block;  // 4096
    loss_synonymy_partial<<<grid, 256, 0, stream>>>(S1, S2, labels, partials, B, D);
    loss_synonymy_reduce<<<1, 256, 0, stream>>>(partials, out, grid);
}